// Round 1
// baseline (182.560 us; speedup 1.0000x reference)
//
#include <hip/hip_runtime.h>
#include <hip/hip_bf16.h>
#include <math.h>

#define L_TAU_C 0.8f

__device__ __forceinline__ float sigmoidf_(float x) {
    return 1.0f / (1.0f + __expf(-x));
}

// ---------------------------------------------------------------------------
// Kernel 1: transpose x [128][4096][20] -> xT [128][20][4096]
// Thread = one pixel p: reads 20 consecutive floats (5x float4, coalesced),
// writes 20 scattered-in-t stores, each coalesced across the wave in p.
// ---------------------------------------------------------------------------
__global__ __launch_bounds__(256) void k_transpose(const float* __restrict__ x,
                                                   float* __restrict__ xT) {
    int gp = blockIdx.x * 256 + threadIdx.x;      // 0..524287
    int b = gp >> 12, p = gp & 4095;
    const float4* src = reinterpret_cast<const float4*>(x + (size_t)gp * 20);
    float v[20];
#pragma unroll
    for (int k = 0; k < 5; ++k) {
        float4 q = src[k];
        v[4 * k + 0] = q.x; v[4 * k + 1] = q.y; v[4 * k + 2] = q.z; v[4 * k + 3] = q.w;
    }
    float* dst = xT + (size_t)b * 20 * 4096 + p;
#pragma unroll
    for (int t = 0; t < 20; ++t) dst[(size_t)t * 4096] = v[t];
}

// ---------------------------------------------------------------------------
// Kernel 2: fused conv + SNU(s1,y1) + maxpool + partial FC dot.
// Grid = 768 blocks = (b, ch), XCD-swizzled so all 6 ch of a batch share an
// XCD (L2 reuse of the x_t slice). Block = 256 threads; 243 active, each owns
// one pool row x 3 pool cols = 2 conv rows x 6 conv cols. s1/y1 live in
// registers across the t loop. Writes part[t][b][ch][2].
// ---------------------------------------------------------------------------
__global__ __launch_bounds__(256) void k_conv_snu(
    const float* __restrict__ xT,   // [128][20][4096] (if use_xT)
    const float* __restrict__ x,    // [128][4096][20] (fallback)
    const float* __restrict__ Wc,   // [6][1][10][10]
    const float* __restrict__ bc,   // [6]
    const float* __restrict__ W2,   // [4374][2]
    float* __restrict__ part,       // [20][128][6][2]
    int use_xT)
{
    __shared__ float xs[64 * 68];   // x_t tile, row stride 68 (bank de-alias)
    __shared__ float wsh[10 * 12];  // conv weights, row stride 12
    __shared__ float red[8];

    const int tid = threadIdx.x;
    const int bi = blockIdx.x;
    const int xcd = bi & 7, slot = bi >> 3;
    const int b = (slot / 6) * 8 + xcd;   // 0..127, all 6 ch of b on same XCD
    const int ch = slot % 6;

    if (tid < 100) wsh[(tid / 10) * 12 + (tid % 10)] = Wc[ch * 100 + tid];

    const bool active = tid < 243;
    const int r = tid / 9;          // pool row 0..26
    const int cg = tid % 9;         // col group 0..8
    const int row0 = r * 2, col0 = cg * 6;

    float s1[2][6], y1[2][6];
#pragma unroll
    for (int i = 0; i < 2; ++i)
#pragma unroll
        for (int j = 0; j < 6; ++j) { s1[i][j] = 0.f; y1[i][j] = 0.f; }

    const float bch = bc[ch];

    float w2r[3][2];
#pragma unroll
    for (int pj = 0; pj < 3; ++pj) { w2r[pj][0] = 0.f; w2r[pj][1] = 0.f; }
    if (active) {
        int f0 = ch * 729 + r * 27 + cg * 3;
#pragma unroll
        for (int pj = 0; pj < 3; ++pj) {
            w2r[pj][0] = W2[(size_t)(f0 + pj) * 2 + 0];
            w2r[pj][1] = W2[(size_t)(f0 + pj) * 2 + 1];
        }
    }

    for (int t = 0; t < 20; ++t) {
        __syncthreads();  // xs reads of t-1 done; red safe; wsh visible (t=0)
        if (use_xT) {
            const float4* src = reinterpret_cast<const float4*>(
                xT + ((size_t)b * 20 + t) * 4096);
#pragma unroll
            for (int k = 0; k < 4; ++k) {
                float4 v = src[tid + k * 256];
                int p = (tid + k * 256) * 4;
                int row = p >> 6, col = p & 63;
                *reinterpret_cast<float4*>(&xs[row * 68 + col]) = v;
            }
        } else {
#pragma unroll
            for (int k = 0; k < 16; ++k) {
                int p = tid + k * 256;
                xs[(p >> 6) * 68 + (p & 63)] = x[((size_t)b * 4096 + p) * 20 + t];
            }
        }
        __syncthreads();

        float p0 = 0.f, p1 = 0.f;
        if (active) {
            float c0[6], c1[6];
#pragma unroll
            for (int j = 0; j < 6; ++j) { c0[j] = 0.f; c1[j] = 0.f; }
            float wprev[10];
#pragma unroll
            for (int xr = 0; xr < 11; ++xr) {
                float seg[15];
                const float* xrow = &xs[(row0 + xr) * 68 + col0];
#pragma unroll
                for (int j = 0; j < 15; ++j) seg[j] = xrow[j];
                float wcur[10];
                if (xr <= 9) {
#pragma unroll
                    for (int kc = 0; kc < 10; ++kc) wcur[kc] = wsh[xr * 12 + kc];
#pragma unroll
                    for (int kc = 0; kc < 10; ++kc)
#pragma unroll
                        for (int j = 0; j < 6; ++j) c0[j] += seg[j + kc] * wcur[kc];
                }
                if (xr >= 1) {
#pragma unroll
                    for (int kc = 0; kc < 10; ++kc)
#pragma unroll
                        for (int j = 0; j < 6; ++j) c1[j] += seg[j + kc] * wprev[kc];
                }
                if (xr <= 9) {
#pragma unroll
                    for (int kc = 0; kc < 10; ++kc) wprev[kc] = wcur[kc];
                }
            }
            // SNU state update: s = relu(c + 0.8*s*(1-y)); y = sigmoid(s + bc)
#pragma unroll
            for (int j = 0; j < 6; ++j) {
                float sa = fmaxf(c0[j] + L_TAU_C * s1[0][j] * (1.f - y1[0][j]), 0.f);
                float sb = fmaxf(c1[j] + L_TAU_C * s1[1][j] * (1.f - y1[1][j]), 0.f);
                s1[0][j] = sa; s1[1][j] = sb;
                y1[0][j] = sigmoidf_(sa + bch);
                y1[1][j] = sigmoidf_(sb + bch);
            }
            // maxpool 2x2 + partial FC dot
#pragma unroll
            for (int pj = 0; pj < 3; ++pj) {
                float h = fmaxf(fmaxf(y1[0][2 * pj], y1[0][2 * pj + 1]),
                                fmaxf(y1[1][2 * pj], y1[1][2 * pj + 1]));
                p0 += h * w2r[pj][0];
                p1 += h * w2r[pj][1];
            }
        }
        // block reduce p0,p1
#pragma unroll
        for (int off = 32; off >= 1; off >>= 1) {
            p0 += __shfl_down(p0, off);
            p1 += __shfl_down(p1, off);
        }
        int wave = tid >> 6;
        if ((tid & 63) == 0) { red[wave * 2] = p0; red[wave * 2 + 1] = p1; }
        __syncthreads();
        if (tid == 0) {
            float q0 = red[0] + red[2] + red[4] + red[6];
            float q1 = red[1] + red[3] + red[5] + red[7];
            float* dst = part + ((size_t)t * 128 + b) * 12 + ch * 2;
            dst[0] = q0; dst[1] = q1;
        }
    }
}

// ---------------------------------------------------------------------------
// Kernel 3: s2/y2 recurrence, out_rec, m, loss, acc. One block, 128 threads.
// ---------------------------------------------------------------------------
__global__ __launch_bounds__(128) void k_final(const float* __restrict__ part,
                                               const void* __restrict__ yraw,
                                               const float* __restrict__ b2,
                                               float* __restrict__ out) {
    __shared__ float red[4];
    const int b = threadIdx.x;  // 0..127

    // labels may be int64 (reference) or int32 (harness downcast): detect.
    const int* yi = (const int*)yraw;
    bool i64 = true;
    for (int k = 0; k < 64; ++k) {
        if (yi[2 * k + 1] != 0) { i64 = false; break; }
    }
    int lbl = i64 ? (int)((const long long*)yraw)[b] : yi[b];

    float b20 = b2[0], b21 = b2[1];
    float s20 = 0.f, s21 = 0.f, y20 = 0.f, y21 = 0.f, m0 = 0.f, m1 = 0.f;
    float* orec = out + 257 + b * 42;
    orec[0] = 0.f; orec[1] = 0.f;
    for (int t = 0; t < 20; ++t) {
        const float4* pp = reinterpret_cast<const float4*>(part + ((size_t)t * 128 + b) * 12);
        float4 a = pp[0], c = pp[1], d = pp[2];
        float sum0 = a.x + a.z + c.x + c.z + d.x + d.z;
        float sum1 = a.y + a.w + c.y + c.w + d.y + d.w;
        s20 = fmaxf(sum0 + L_TAU_C * s20 * (1.f - y20), 0.f);
        s21 = fmaxf(sum1 + L_TAU_C * s21 * (1.f - y21), 0.f);
        y20 = sigmoidf_(s20 + b20);
        y21 = sigmoidf_(s21 + b21);
        orec[(t + 1) * 2 + 0] = y20;
        orec[(t + 1) * 2 + 1] = y21;
        m0 += y20; m1 += y21;
    }
    m0 *= 0.05f; m1 *= 0.05f;
    out[1 + b * 2 + 0] = m0;
    out[1 + b * 2 + 1] = m1;

    float mx = fmaxf(m0, m1);
    float lse = mx + logf(expf(m0 - mx) + expf(m1 - mx));
    float lossc = -(((lbl != 0) ? m1 : m0) - lse);
    int pred = (m1 > m0) ? 1 : 0;
    float accc = (pred == lbl) ? 1.f : 0.f;
#pragma unroll
    for (int off = 32; off >= 1; off >>= 1) {
        lossc += __shfl_down(lossc, off);
        accc += __shfl_down(accc, off);
    }
    if ((b & 63) == 0) { red[(b >> 6) * 2] = lossc; red[(b >> 6) * 2 + 1] = accc; }
    __syncthreads();
    if (b == 0) {
        out[0] = (red[0] + red[2]) * (1.f / 128.f);
        out[5633] = (red[1] + red[3]) * (1.f / 128.f);
    }
}

extern "C" void kernel_launch(void* const* d_in, const int* in_sizes, int n_in,
                              void* d_out, int out_size, void* d_ws, size_t ws_size,
                              hipStream_t stream) {
    const float* x  = (const float*)d_in[0];
    const void*  y  = d_in[1];
    const float* Wc = (const float*)d_in[2];
    const float* bc = (const float*)d_in[3];
    const float* W2 = (const float*)d_in[4];
    const float* b2 = (const float*)d_in[5];
    float* out = (float*)d_out;

    const size_t xT_floats = (size_t)128 * 20 * 4096;        // 10,485,760
    const size_t need = (xT_floats + 20 * 128 * 6 * 2) * 4;  // ~42.07 MB
    const int use_xT = (ws_size >= need) ? 1 : 0;

    float* xT = (float*)d_ws;
    float* part = use_xT ? ((float*)d_ws + xT_floats) : (float*)d_ws;

    if (use_xT) {
        k_transpose<<<2048, 256, 0, stream>>>(x, xT);
    }
    k_conv_snu<<<768, 256, 0, stream>>>(xT, x, Wc, bc, W2, part, use_xT);
    k_final<<<1, 128, 0, stream>>>(part, y, b2, out);
}